// Round 3
// baseline (3273.886 us; speedup 1.0000x reference)
//
#include <hip/hip_runtime.h>
#include <hip/hip_bf16.h>
#include <cstdint>
#include <cstddef>

static constexpr int NN  = 8192;    // total nodes
static constexpr int EE  = 131072;  // edges
static constexpr float SLOPE  = 0.2f;
static constexpr float LN_EPS = 1e-5f;

#define DEVI __device__ __forceinline__

DEVI float red32(float v) {   // sum over 32-lane half (lanes stay in their half)
  #pragma unroll
  for (int m = 16; m >= 1; m >>= 1) v += __shfl_xor(v, m, 64);
  return v;
}
DEVI float red64(float v) {   // sum over full wave
  #pragma unroll
  for (int m = 32; m >= 1; m >>= 1) v += __shfl_xor(v, m, 64);
  return v;
}
DEVI float max32(float v) {
  #pragma unroll
  for (int m = 16; m >= 1; m >>= 1) v = fmaxf(v, __shfl_xor(v, m, 64));
  return v;
}

// ---------------------------------------------------------------------------
// FC: gh[n] = feat_t[n] @ Wfc_t + bfc_t   (32 nodes per block, type-uniform)
// epilogue: out[n, 0:256] = l2n(gh[n])
// ---------------------------------------------------------------------------
__global__ __launch_bounds__(256) void fc_kernel(
    const float* __restrict__ f0, const float* __restrict__ f1,
    const float* __restrict__ f2, const float* __restrict__ f3,
    const float* __restrict__ w0, const float* __restrict__ w1,
    const float* __restrict__ w2, const float* __restrict__ w3,
    const float* __restrict__ b0, const float* __restrict__ b1,
    const float* __restrict__ b2, const float* __restrict__ b3,
    float* __restrict__ gh, float* __restrict__ out)
{
  const int nb = blockIdx.x * 32;
  const int t  = threadIdx.x;
  int base, D;
  const float *F, *W, *Bv;
  if (nb < 4096)      { base = 0;    D = 128; F = f0; W = w0; Bv = b0; }
  else if (nb < 6144) { base = 4096; D = 64;  F = f1; W = w1; Bv = b1; }
  else if (nb < 7168) { base = 6144; D = 32;  F = f2; W = w2; Bv = b2; }
  else                { base = 7168; D = 16;  F = f3; W = w3; Bv = b3; }

  __shared__ float Fs[32 * 128];
  __shared__ float red[32][4];
  __shared__ float nrm[32];

  const int total = 32 * D;
  for (int i = t; i < total; i += 256) Fs[i] = F[(size_t)(nb - base) * D + i];
  __syncthreads();

  float acc[32];
  #pragma unroll
  for (int r = 0; r < 32; ++r) acc[r] = Bv[t];
  for (int d = 0; d < D; ++d) {
    float w = W[(size_t)d * 256 + t];
    #pragma unroll
    for (int r = 0; r < 32; ++r) acc[r] = fmaf(Fs[r * D + d], w, acc[r]);
  }

  const int lane = t & 63, wid = t >> 6;
  #pragma unroll
  for (int r = 0; r < 32; ++r) {
    float v = acc[r] * acc[r];
    for (int o = 32; o > 0; o >>= 1) v += __shfl_down(v, o, 64);
    if (lane == 0) red[r][wid] = v;
  }
  __syncthreads();
  if (t < 32) {
    float s = red[t][0] + red[t][1] + red[t][2] + red[t][3];
    nrm[t] = 1.0f / fmaxf(sqrtf(s), 1e-12f);
  }
  __syncthreads();
  #pragma unroll
  for (int r = 0; r < 32; ++r) {
    gh[(size_t)(nb + r) * 256 + t]  = acc[r];
    out[(size_t)(nb + r) * 768 + t] = acc[r] * nrm[r];
  }
}

// ---------------------------------------------------------------------------
// degree / CSR build
// ---------------------------------------------------------------------------
__global__ __launch_bounds__(256) void zero_counts(int* outc, int* inc) {
  int g = blockIdx.x * 256 + threadIdx.x;
  if (g < NN) outc[g] = 0; else inc[g - NN] = 0;
}
__global__ __launch_bounds__(256) void count_deg(const int* __restrict__ src,
                                                 const int* __restrict__ dst,
                                                 int* outc, int* inc) {
  int g = blockIdx.x * 256 + threadIdx.x;
  atomicAdd(&outc[src[g]], 1);
  atomicAdd(&inc[dst[g]], 1);
}
__global__ __launch_bounds__(256) void norm_kernel(const int* __restrict__ outc,
                                                   const int* __restrict__ inc,
                                                   float* n_out, float* n_in) {
  int g = blockIdx.x * 256 + threadIdx.x;
  n_out[g] = rsqrtf((float)outc[g] + 1.0f);   // +1 self-loop, always >=1
  n_in[g]  = rsqrtf((float)inc[g] + 1.0f);
}
__global__ __launch_bounds__(1024) void scan_kernel(const int* __restrict__ inc,
                                                    int* __restrict__ offs) {
  __shared__ int sums[1024];
  const int t = threadIdx.x;
  int x[8];
  const int base = t * 8;
  int s = 0;
  #pragma unroll
  for (int i = 0; i < 8; ++i) { int v = inc[base + i] + 1; x[i] = s; s += v; }
  sums[t] = s;
  __syncthreads();
  for (int off = 1; off < 1024; off <<= 1) {
    int a = (t >= off) ? sums[t - off] : 0;
    __syncthreads();
    sums[t] += a;
    __syncthreads();
  }
  const int pre = (t > 0) ? sums[t - 1] : 0;
  #pragma unroll
  for (int i = 0; i < 8; ++i) offs[base + i] = pre + x[i];
  if (t == 1023) offs[NN] = sums[1023];
}
__global__ __launch_bounds__(256) void copy_cur(const int* __restrict__ offs, int* cur) {
  int g = blockIdx.x * 256 + threadIdx.x;
  cur[g] = offs[g];
}
__global__ __launch_bounds__(256) void fill_csr(const int* __restrict__ src,
                                                const int* __restrict__ dst,
                                                int* cur, int* __restrict__ csr) {
  int g = blockIdx.x * 256 + threadIdx.x;   // EE + NN total
  int s, d;
  if (g < EE) { s = src[g]; d = dst[g]; }
  else        { s = g - EE; d = g - EE; }   // self-loops
  int pos = atomicAdd(&cur[d], 1);
  csr[pos] = s;
}
__global__ __launch_bounds__(256) void init_R(const float* __restrict__ type_emb,
                                              const int* __restrict__ nt,
                                              float* __restrict__ R) {
  int g = blockIdx.x * 256 + threadIdx.x;   // NN*4
  int n = g >> 2, c = g & 3;
  R[g] = type_emb[nt[n] * 4 + c];
}

// ---------------------------------------------------------------------------
// [8192,256] @ [256,256] f32 register-tiled GEMM, 64x64 tile, 256 thr.
// Optional: row-scale (GCN n_out), store C, per-head leakyrelu·avec -> SS[M,8]
// ---------------------------------------------------------------------------
template<bool ROWSCALE, bool STORE, bool RED>
__global__ __launch_bounds__(256) void gemm64_kernel(
    const float* __restrict__ A,
    const float* __restrict__ W,
    const float* __restrict__ rowscale,
    float* __restrict__ C,
    const float* __restrict__ avec,
    float* __restrict__ SSo)
{
  const int m0 = blockIdx.x * 64;
  const int n0 = blockIdx.y * 64;
  const int t  = threadIdx.x;
  const int tr = t & 15, tc = t >> 4;
  __shared__ alignas(16) float As[32][68];
  __shared__ alignas(16) float Bs[32][68];
  __shared__ float red[64][2];
  float acc[4][4] = {};

  for (int ks = 0; ks < 8; ++ks) {
    const int k0 = ks * 32;
    #pragma unroll
    for (int rep = 0; rep < 8; ++rep) {
      int flat = rep * 256 + t;
      int r = flat >> 5, c = flat & 31;
      As[c][r] = A[(size_t)(m0 + r) * 256 + (k0 + c)];
      int rb = flat >> 6, cb = flat & 63;
      Bs[rb][cb] = W[(size_t)(k0 + rb) * 256 + (n0 + cb)];
    }
    __syncthreads();
    #pragma unroll
    for (int k = 0; k < 32; ++k) {
      const float4 a4 = *reinterpret_cast<const float4*>(&As[k][tr * 4]);
      const float4 b4 = *reinterpret_cast<const float4*>(&Bs[k][tc * 4]);
      const float av[4] = {a4.x, a4.y, a4.z, a4.w};
      const float bv[4] = {b4.x, b4.y, b4.z, b4.w};
      #pragma unroll
      for (int u = 0; u < 4; ++u)
        #pragma unroll
        for (int v = 0; v < 4; ++v)
          acc[u][v] = fmaf(av[u], bv[v], acc[u][v]);
    }
    __syncthreads();
  }

  if constexpr (ROWSCALE) {
    #pragma unroll
    for (int u = 0; u < 4; ++u) {
      float s = rowscale[m0 + tr * 4 + u];
      #pragma unroll
      for (int v = 0; v < 4; ++v) acc[u][v] *= s;
    }
  }
  if constexpr (STORE) {
    #pragma unroll
    for (int u = 0; u < 4; ++u) {
      size_t row = (size_t)(m0 + tr * 4 + u);
      #pragma unroll
      for (int v = 0; v < 4; ++v)
        C[row * 256 + (n0 + tc * 4 + v)] = acc[u][v];
    }
  }
  if constexpr (RED) {
    if (t < 128) red[t >> 1][t & 1] = 0.f;
    __syncthreads();
    #pragma unroll
    for (int u = 0; u < 4; ++u) {
      float s = 0.f;
      #pragma unroll
      for (int v = 0; v < 4; ++v) {
        float x = acc[u][v];
        float lr = x > 0.f ? x : SLOPE * x;
        s += lr * avec[(tc * 4 + v) & 31];
      }
      atomicAdd(&red[tr * 4 + u][tc >> 3], s);
    }
    __syncthreads();
    if (t < 128) {
      int r = t >> 1, hh = t & 1;
      SSo[(size_t)(m0 + r) * 8 + blockIdx.y * 2 + hh] = red[r][hh];
    }
  }
}

// ---------------------------------------------------------------------------
// GCN aggregate: gh[n] = relu( (sum_{CSR(n)} X[s]) * n_in[n] + b )  (in place)
// ---------------------------------------------------------------------------
__global__ __launch_bounds__(256) void agg_kernel(
    const int* __restrict__ offs, const int* __restrict__ csr,
    const float* __restrict__ X, const float* __restrict__ n_in,
    const float* __restrict__ bias, float* __restrict__ ghn)
{
  const int n = blockIdx.x, t = threadIdx.x;
  const int s0 = offs[n], s1 = offs[n + 1];
  float acc = 0.f;
  for (int i = s0; i < s1; ++i) {
    int s = csr[i];
    acc += X[(size_t)s * 256 + t];
  }
  ghn[(size_t)n * 256 + t] = fmaxf(fmaf(acc, n_in[n], bias[t]), 0.f);
}

// REConv: project then aggregate (4 channels, in-place on R via rtmp)
__global__ __launch_bounds__(256) void re_proj(
    const float* __restrict__ R, const float* __restrict__ n_out,
    const float* __restrict__ Wre, const float* __restrict__ wtre,
    const int* __restrict__ nt, float* __restrict__ rtmp)
{
  int g = blockIdx.x * 256 + threadIdx.x;  // NN*4
  int n = g >> 2, j = g & 3;
  float s = 0.f;
  #pragma unroll
  for (int c = 0; c < 4; ++c) s += R[n * 4 + c] * Wre[c * 4 + j];
  rtmp[g] = s * n_out[n] * wtre[nt[n]];
}
__global__ __launch_bounds__(256) void re_agg(
    const int* __restrict__ offs, const int* __restrict__ csr,
    const float* __restrict__ rtmp, const float* __restrict__ n_in,
    const float* __restrict__ bre, float* __restrict__ Rn)
{
  int g = blockIdx.x * 256 + threadIdx.x;  // NN*4
  int n = g >> 2, j = g & 3;
  float a = 0.f;
  for (int i = offs[n]; i < offs[n + 1]; ++i) a += rtmp[csr[i] * 4 + j];
  Rn[g] = fmaxf(fmaf(a, n_in[n], bre[j]), 0.f);
}

// RKQ[n][0:32]=R@Wrs0 [32:64]=R@Wrt0 [64:96]=R@Wrs1 [96:128]=R@Wrt1
__global__ __launch_bounds__(256) void rkq_kernel(
    const float* __restrict__ R, const float* __restrict__ Wrs,
    const float* __restrict__ Wrt, float* __restrict__ RKQ)
{
  int g = blockIdx.x * 256 + threadIdx.x;  // NN*128
  int n = g >> 7, c = g & 127;
  int which = c >> 5, cc = c & 31;
  const float* Wp = (which == 0) ? Wrs : (which == 1) ? Wrt
                   : (which == 2) ? (Wrs + 128) : (Wrt + 128);
  float s = 0.f;
  #pragma unroll
  for (int r = 0; r < 4; ++r) s += R[n * 4 + r] * Wp[r * 32 + cc];
  RKQ[g] = s;
}

// ---------------------------------------------------------------------------
// MEGA: per batch b (one block, 256 threads, ~110 KB LDS):
//   attn1 -> hsa (LDS) -> @Wfin1 + res + LN -> h1 (LDS), ret1 row0
//   -> FR2 = h1@Wr2 (LDS) + SR2; fl2 row0 -> sl2; attn2 row0 -> ctx2
//   -> @Wfin2 + res + LN + l2n -> ret2.  Nothing batch-local hits HBM.
// ---------------------------------------------------------------------------
__global__ __launch_bounds__(256) void mega_kernel(
    const int* __restrict__ seqs,
    const float* __restrict__ gh,
    const float* __restrict__ GR1,
    const float* __restrict__ SLg, const float* __restrict__ SRg,
    const float* __restrict__ RKQ,
    const float* __restrict__ Wfin,   // [2][256][256], layer0 base
    const float* __restrict__ Wr2,    // Wr + 65536
    const float* __restrict__ Wl2,    // Wl + 65536
    const float* __restrict__ al2, const float* __restrict__ ar2, // +32
    const float* __restrict__ ln_g, const float* __restrict__ ln_b, // [2][256]
    float* __restrict__ out)
{
  __shared__ int   idx[32];
  __shared__ float A1[32][256];   // FR1, then h1
  __shared__ float A2[32][256];   // hsa, then FR2
  __shared__ float Ws[32][260];   // weight k-slice stage (pad 260 -> bank-free)
  __shared__ float SLs[8][32];
  __shared__ float SRs[8][32];    // SR1, then SR2[head][row]
  __shared__ float RKs[32][36];
  __shared__ float RQs[32][36];   // RQ1, then RQ2
  __shared__ float rk2s[32];
  __shared__ float scp[8][33];
  __shared__ float ctx2s[256];
  __shared__ float wred[8];       // sl2[h], then l2n partials
  __shared__ float misc2[8];

  const int b = blockIdx.x, t = threadIdx.x;
  const int h8 = t >> 5, lo = t & 31;

  if (t < 32) idx[t] = seqs[b * 32 + t];
  __syncthreads();

  for (int s = 0; s < 32; ++s) A1[s][t] = GR1[(size_t)idx[s] * 256 + t];
  SLs[h8][lo] = SLg[(size_t)idx[lo] * 8 + h8];
  SRs[h8][lo] = SRg[(size_t)idx[lo] * 8 + h8];
  #pragma unroll
  for (int rep = 0; rep < 4; ++rep) {
    int flat = rep * 256 + t, s3 = flat >> 5, c3 = flat & 31;
    RKs[s3][c3] = RKQ[(size_t)idx[s3] * 128 + c3];
    RQs[s3][c3] = RKQ[(size_t)idx[s3] * 128 + 32 + c3];
  }
  __syncthreads();

  // ---- attn1: thread = (head h8, query row lo) ----
  {
    const float rk0 = RKs[lo][h8 * 4 + 0], rk1 = RKs[lo][h8 * 4 + 1],
                rk2 = RKs[lo][h8 * 4 + 2], rk3 = RKs[lo][h8 * 4 + 3];
    const float sli = SLs[h8][lo];
    float p[32], m = -1e30f;
    #pragma unroll
    for (int j = 0; j < 32; ++j) {
      float sc = sli + SRs[h8][j]
               + rk0 * RQs[j][h8 * 4 + 0] + rk1 * RQs[j][h8 * 4 + 1]
               + rk2 * RQs[j][h8 * 4 + 2] + rk3 * RQs[j][h8 * 4 + 3];
      p[j] = sc; m = fmaxf(m, sc);
    }
    float sum = 0.f;
    #pragma unroll
    for (int j = 0; j < 32; ++j) { p[j] = __expf(p[j] - m); sum += p[j]; }
    const float inv = 1.f / sum;
    #pragma unroll
    for (int dd = 0; dd < 32; ++dd) {
      int d = (dd + lo) & 31;               // rotate: bank-spread
      float a = 0.f;
      #pragma unroll
      for (int j = 0; j < 32; ++j) a = fmaf(p[j], A1[j][h8 * 32 + d], a);
      A2[lo][h8 * 32 + d] = a * inv;
    }
  }
  __syncthreads();

  // ---- GEMM1: h1 = LN(hsa @ Wfin1 + gh[idx]) -> A1 ; ret1 from row 0 ----
  float acc[4][8];
  #pragma unroll
  for (int u = 0; u < 4; ++u)
    #pragma unroll
    for (int q = 0; q < 8; ++q) acc[u][q] = 0.f;
  for (int kb = 0; kb < 8; ++kb) {
    #pragma unroll
    for (int rep = 0; rep < 32; ++rep)
      Ws[rep][t] = Wfin[(size_t)(kb * 32 + rep) * 256 + t];
    __syncthreads();
    #pragma unroll 4
    for (int kk = 0; kk < 32; ++kk) {
      const int k = kb * 32 + kk;
      const float a0 = A2[h8 * 4 + 0][k], a1 = A2[h8 * 4 + 1][k],
                  a2 = A2[h8 * 4 + 2][k], a3 = A2[h8 * 4 + 3][k];
      #pragma unroll
      for (int q = 0; q < 8; ++q) {
        const float w = Ws[kk][lo + 32 * q];
        acc[0][q] = fmaf(a0, w, acc[0][q]);
        acc[1][q] = fmaf(a1, w, acc[1][q]);
        acc[2][q] = fmaf(a2, w, acc[2][q]);
        acc[3][q] = fmaf(a3, w, acc[3][q]);
      }
    }
    __syncthreads();
  }
  {
    float y0[8];
    #pragma unroll
    for (int q = 0; q < 8; ++q) y0[q] = 0.f;
    #pragma unroll
    for (int u = 0; u < 4; ++u) {
      const int r = h8 * 4 + u;
      const float* gp = &gh[(size_t)idx[r] * 256];
      float s = 0.f;
      #pragma unroll
      for (int q = 0; q < 8; ++q) { acc[u][q] += gp[lo + 32 * q]; s += acc[u][q]; }
      s = red32(s);
      const float mu = s * (1.f / 256.f);
      float v = 0.f;
      #pragma unroll
      for (int q = 0; q < 8; ++q) { float d2 = acc[u][q] - mu; v += d2 * d2; }
      v = red32(v);
      const float rstd = rsqrtf(v * (1.f / 256.f) + LN_EPS);
      #pragma unroll
      for (int q = 0; q < 8; ++q) {
        const int c = lo + 32 * q;
        const float y = fmaf((acc[u][q] - mu) * rstd, ln_g[c], ln_b[c]);
        A1[r][c] = y;
        if (r == 0) y0[q] = y;
      }
    }
    if (h8 == 0) {   // lanes 0..31 of wave 0 hold row 0 (u==0)
      float sq = 0.f;
      #pragma unroll
      for (int q = 0; q < 8; ++q) sq += y0[q] * y0[q];
      sq = red32(sq);
      const float nrm = 1.f / fmaxf(sqrtf(sq), 1e-12f);
      #pragma unroll
      for (int q = 0; q < 8; ++q)
        out[(size_t)b * 768 + 256 + lo + 32 * q] = y0[q] * nrm;
    }
  }
  __syncthreads();

  // ---- GEMM2: FR2 = h1 @ Wr2 -> A2 ; SR2 -> SRs[head][row] ----
  #pragma unroll
  for (int u = 0; u < 4; ++u)
    #pragma unroll
    for (int q = 0; q < 8; ++q) acc[u][q] = 0.f;
  for (int kb = 0; kb < 8; ++kb) {
    #pragma unroll
    for (int rep = 0; rep < 32; ++rep)
      Ws[rep][t] = Wr2[(size_t)(kb * 32 + rep) * 256 + t];
    __syncthreads();
    #pragma unroll 4
    for (int kk = 0; kk < 32; ++kk) {
      const int k = kb * 32 + kk;
      const float a0 = A1[h8 * 4 + 0][k], a1 = A1[h8 * 4 + 1][k],
                  a2 = A1[h8 * 4 + 2][k], a3 = A1[h8 * 4 + 3][k];
      #pragma unroll
      for (int q = 0; q < 8; ++q) {
        const float w = Ws[kk][lo + 32 * q];
        acc[0][q] = fmaf(a0, w, acc[0][q]);
        acc[1][q] = fmaf(a1, w, acc[1][q]);
        acc[2][q] = fmaf(a2, w, acc[2][q]);
        acc[3][q] = fmaf(a3, w, acc[3][q]);
      }
    }
    __syncthreads();
  }
  {
    const float arc = ar2[lo];
    #pragma unroll
    for (int u = 0; u < 4; ++u) {
      const int r = h8 * 4 + u;
      #pragma unroll
      for (int q = 0; q < 8; ++q) {
        const float x = acc[u][q];
        A2[r][lo + 32 * q] = x;
        float v = (x > 0.f ? x : SLOPE * x) * arc;
        v = red32(v);
        if (lo == 0) SRs[q][r] = v;   // head q (= col/32), key row r
      }
    }
  }
  // ---- fl2 (row 0 of h1) -> sl2 ; load RQ2 / rk2 ----
  {
    float f = 0.f;
    #pragma unroll 4
    for (int k = 0; k < 256; ++k) f = fmaf(A1[0][k], Wl2[(size_t)k * 256 + t], f);
    float v = (f > 0.f ? f : SLOPE * f) * al2[lo];
    v = red32(v);
    if (lo == 0) wred[h8] = v;        // sl2[h]
  }
  #pragma unroll
  for (int rep = 0; rep < 4; ++rep) {
    int flat = rep * 256 + t, s3 = flat >> 5, c3 = flat & 31;
    RQs[s3][c3] = RKQ[(size_t)idx[s3] * 128 + 96 + c3];
  }
  if (t < 32) rk2s[t] = RKQ[(size_t)idx[0] * 128 + 64 + t];
  __syncthreads();

  // ---- attn2 row 0: scores + softmax (thread = (h8, key lo)) ----
  {
    float s = wred[h8] + SRs[h8][lo]
            + rk2s[h8 * 4 + 0] * RQs[lo][h8 * 4 + 0]
            + rk2s[h8 * 4 + 1] * RQs[lo][h8 * 4 + 1]
            + rk2s[h8 * 4 + 2] * RQs[lo][h8 * 4 + 2]
            + rk2s[h8 * 4 + 3] * RQs[lo][h8 * 4 + 3];
    float m = max32(s);
    float e = __expf(s - m);
    float sum = red32(e);
    scp[h8][lo] = e / sum;
  }
  __syncthreads();
  // ---- ctx2 = p @ FR2 (thread = col t) ----
  {
    const int hh = t >> 5;
    float a = 0.f;
    #pragma unroll
    for (int j = 0; j < 32; ++j) a = fmaf(scp[hh][j], A2[j][t], a);
    ctx2s[t] = a;
  }
  __syncthreads();
  // ---- h2 = LN(h1row0 + ctx2 @ Wfin2) ; ret2 = l2n(h2) ----
  {
    const float* W4 = Wfin + 65536;
    float y = 0.f;
    #pragma unroll 4
    for (int k = 0; k < 256; ++k) y = fmaf(ctx2s[k], W4[(size_t)k * 256 + t], y);
    y += A1[0][t];
    float s = red64(y);
    if ((t & 63) == 0) misc2[t >> 6] = s;
    __syncthreads();
    const float mu = (misc2[0] + misc2[1] + misc2[2] + misc2[3]) * (1.f / 256.f);
    const float d = y - mu;
    s = red64(d * d);
    if ((t & 63) == 0) misc2[4 + (t >> 6)] = s;
    __syncthreads();
    const float rstd = rsqrtf((misc2[4] + misc2[5] + misc2[6] + misc2[7]) * (1.f / 256.f) + LN_EPS);
    const float yn = fmaf(d * rstd, ln_g[256 + t], ln_b[256 + t]);
    s = red64(yn * yn);
    if ((t & 63) == 0) wred[4 + (t >> 6)] = s;
    __syncthreads();
    const float nrm = 1.f / fmaxf(sqrtf(wred[4] + wred[5] + wred[6] + wred[7]), 1e-12f);
    out[(size_t)b * 768 + 512 + t] = yn * nrm;
  }
}

// ---------------------------------------------------------------------------
extern "C" void kernel_launch(void* const* d_in, const int* in_sizes, int n_in,
                              void* d_out, int out_size, void* d_ws, size_t ws_size,
                              hipStream_t stream)
{
  (void)in_sizes; (void)n_in; (void)out_size; (void)ws_size;

  // setup_inputs() dict order: (feat,Wfc,bfc) x4, then the rest.
  const float* feat[4]; const float* wfc[4]; const float* bfc[4];
  for (int i = 0; i < 4; ++i) {
    feat[i] = (const float*)d_in[i * 3 + 0];
    wfc[i]  = (const float*)d_in[i * 3 + 1];
    bfc[i]  = (const float*)d_in[i * 3 + 2];
  }
  const float* type_emb = (const float*)d_in[12];
  const float* Wgcn = (const float*)d_in[13];
  const float* bgcn = (const float*)d_in[14];
  const float* Wre  = (const float*)d_in[15];
  const float* bre  = (const float*)d_in[16];
  const float* wtre = (const float*)d_in[17];
  const float* Wl   = (const float*)d_in[18];
  const float* Wr   = (const float*)d_in[19];
  const float* al   = (const float*)d_in[20];
  const float* ar   = (const float*)d_in[21];
  const float* Wrs  = (const float*)d_in[22];
  const float* Wrt  = (const float*)d_in[23];
  const float* Wfin = (const float*)d_in[24];
  const float* ln_g = (const float*)d_in[25];
  const float* ln_b = (const float*)d_in[26];
  const int* src       = (const int*)d_in[27];
  const int* dst       = (const int*)d_in[28];
  const int* node_type = (const int*)d_in[29];
  const int* seqs      = (const int*)d_in[30];
  float* out = (float*)d_out;

  // workspace carve-up (~30 MB total)
  char* p = (char*)d_ws;
  auto take = [&](size_t n) { char* q = p; p += (n + 255) & ~(size_t)255; return q; };
  float* gh    = (float*)take((size_t)NN * 256 * 4);    // 8 MB
  float* Xbuf  = (float*)take((size_t)NN * 256 * 4);    // 8 MB
  float* GR1   = (float*)take((size_t)NN * 256 * 4);    // 8 MB
  float* RKQ   = (float*)take((size_t)NN * 128 * 4);    // 4 MB
  float* SLg   = (float*)take((size_t)NN * 8 * 4);
  float* SRg   = (float*)take((size_t)NN * 8 * 4);
  float* n_out = (float*)take((size_t)NN * 4);
  float* n_in_ = (float*)take((size_t)NN * 4);
  int*   outc  = (int*)take((size_t)NN * 4);
  int*   inc   = (int*)take((size_t)NN * 4);
  int*   offs  = (int*)take((size_t)(NN + 1) * 4);
  int*   cur   = (int*)take((size_t)NN * 4);
  int*   csr   = (int*)take((size_t)(EE + NN) * 4);
  float* R     = (float*)take((size_t)NN * 4 * 4);
  float* rtmp  = (float*)take((size_t)NN * 4 * 4);

  // 1) FC + ret0
  fc_kernel<<<256, 256, 0, stream>>>(feat[0], feat[1], feat[2], feat[3],
                                     wfc[0], wfc[1], wfc[2], wfc[3],
                                     bfc[0], bfc[1], bfc[2], bfc[3], gh, out);
  // 2) degrees + CSR
  zero_counts<<<64, 256, 0, stream>>>(outc, inc);
  count_deg<<<512, 256, 0, stream>>>(src, dst, outc, inc);
  norm_kernel<<<32, 256, 0, stream>>>(outc, inc, n_out, n_in_);
  scan_kernel<<<1, 1024, 0, stream>>>(inc, offs);
  copy_cur<<<32, 256, 0, stream>>>(offs, cur);
  fill_csr<<<544, 256, 0, stream>>>(src, dst, cur, csr);
  init_R<<<128, 256, 0, stream>>>(type_emb, node_type, R);

  // 3) GCN + REConv, K=2 (in-place on gh / R via Xbuf / rtmp)
  for (int k = 0; k < 2; ++k) {
    gemm64_kernel<true, true, false>
        <<<dim3(128, 4), 256, 0, stream>>>(gh, Wgcn + (size_t)k * 65536,
                                           n_out, Xbuf, nullptr, nullptr);
    agg_kernel<<<NN, 256, 0, stream>>>(offs, csr, Xbuf, n_in_, bgcn + k * 256, gh);
    re_proj<<<128, 256, 0, stream>>>(R, n_out, Wre + k * 16, wtre + k * 4, node_type, rtmp);
    re_agg<<<128, 256, 0, stream>>>(offs, csr, rtmp, n_in_, bre + k * 4, R);
  }

  // 4) attention precomputes on node tables (gather trick: (gh@W)[seqs])
  gemm64_kernel<false, false, true>
      <<<dim3(128, 4), 256, 0, stream>>>(gh, Wl, nullptr, nullptr, al, SLg);
  gemm64_kernel<false, true, true>
      <<<dim3(128, 4), 256, 0, stream>>>(gh, Wr, nullptr, GR1, ar, SRg);
  rkq_kernel<<<4096, 256, 0, stream>>>(R, Wrs, Wrt, RKQ);

  // 5) fused two-layer transformer, one batch per block
  mega_kernel<<<NN, 256, 0, stream>>>(seqs, gh, GR1, SLg, SRg, RKQ,
                                      Wfin, Wr + 65536, Wl + 65536,
                                      al + 32, ar + 32, ln_g, ln_b, out);
}

// Round 4
// 1475.739 us; speedup vs baseline: 2.2185x; 2.2185x over previous
//
#include <hip/hip_runtime.h>
#include <hip/hip_bf16.h>
#include <cstdint>
#include <cstddef>

typedef unsigned short ushortT;
typedef unsigned int uintT;

static constexpr int NN  = 8192;    // total nodes
static constexpr int EE  = 131072;  // edges
static constexpr float SLOPE  = 0.2f;
static constexpr float LN_EPS = 1e-5f;

#define DEVI __device__ __forceinline__

DEVI float red32(float v) {   // sum within 32-lane half
  #pragma unroll
  for (int m = 16; m >= 1; m >>= 1) v += __shfl_xor(v, m, 64);
  return v;
}
DEVI float max32(float v) {
  #pragma unroll
  for (int m = 16; m >= 1; m >>= 1) v = fmaxf(v, __shfl_xor(v, m, 64));
  return v;
}
DEVI float blo(uintT u) { union { uintT i; float f; } c; c.i = u << 16; return c.f; }
DEVI float bhi(uintT u) { union { uintT i; float f; } c; c.i = u & 0xffff0000u; return c.f; }
DEVI float b2f(ushortT u) { union { uintT i; float f; } c; c.i = ((uintT)u) << 16; return c.f; }
DEVI ushortT f2bu(float f) {
  __hip_bfloat16 h = __float2bfloat16(f);
  return *reinterpret_cast<ushortT*>(&h);
}
DEVI void storeC(float* p, float v) { *p = v; }
DEVI void storeC(ushortT* p, float v) { *p = f2bu(v); }

// ---------------------------------------------------------------------------
// FC: gh[n] = feat_t[n] @ Wfc_t + bfc_t ; out[n,0:256] = l2n(gh[n])
// ---------------------------------------------------------------------------
__global__ __launch_bounds__(256) void fc_kernel(
    const float* __restrict__ f0, const float* __restrict__ f1,
    const float* __restrict__ f2, const float* __restrict__ f3,
    const float* __restrict__ w0, const float* __restrict__ w1,
    const float* __restrict__ w2, const float* __restrict__ w3,
    const float* __restrict__ b0, const float* __restrict__ b1,
    const float* __restrict__ b2, const float* __restrict__ b3,
    float* __restrict__ gh, float* __restrict__ out)
{
  const int nb = blockIdx.x * 32;
  const int t  = threadIdx.x;
  int base, D;
  const float *F, *W, *Bv;
  if (nb < 4096)      { base = 0;    D = 128; F = f0; W = w0; Bv = b0; }
  else if (nb < 6144) { base = 4096; D = 64;  F = f1; W = w1; Bv = b1; }
  else if (nb < 7168) { base = 6144; D = 32;  F = f2; W = w2; Bv = b2; }
  else                { base = 7168; D = 16;  F = f3; W = w3; Bv = b3; }

  __shared__ float Fs[32 * 128];
  __shared__ float red[32][4];
  __shared__ float nrm[32];

  const int total = 32 * D;
  for (int i = t; i < total; i += 256) Fs[i] = F[(size_t)(nb - base) * D + i];
  __syncthreads();

  float acc[32];
  #pragma unroll
  for (int r = 0; r < 32; ++r) acc[r] = Bv[t];
  for (int d = 0; d < D; ++d) {
    float w = W[(size_t)d * 256 + t];
    #pragma unroll
    for (int r = 0; r < 32; ++r) acc[r] = fmaf(Fs[r * D + d], w, acc[r]);
  }

  const int lane = t & 63, wid = t >> 6;
  #pragma unroll
  for (int r = 0; r < 32; ++r) {
    float v = acc[r] * acc[r];
    for (int o = 32; o > 0; o >>= 1) v += __shfl_down(v, o, 64);
    if (lane == 0) red[r][wid] = v;
  }
  __syncthreads();
  if (t < 32) {
    float s = red[t][0] + red[t][1] + red[t][2] + red[t][3];
    nrm[t] = 1.0f / fmaxf(sqrtf(s), 1e-12f);
  }
  __syncthreads();
  #pragma unroll
  for (int r = 0; r < 32; ++r) {
    gh[(size_t)(nb + r) * 256 + t]  = acc[r];
    out[(size_t)(nb + r) * 768 + t] = acc[r] * nrm[r];
  }
}

// ---------------------------------------------------------------------------
// degree / CSR build
// ---------------------------------------------------------------------------
__global__ __launch_bounds__(256) void zero_counts(int* outc, int* inc) {
  int g = blockIdx.x * 256 + threadIdx.x;
  if (g < NN) outc[g] = 0; else inc[g - NN] = 0;
}
__global__ __launch_bounds__(256) void count_deg(const int* __restrict__ src,
                                                 const int* __restrict__ dst,
                                                 int* outc, int* inc) {
  int g = blockIdx.x * 256 + threadIdx.x;
  atomicAdd(&outc[src[g]], 1);
  atomicAdd(&inc[dst[g]], 1);
}
__global__ __launch_bounds__(256) void norm_kernel(const int* __restrict__ outc,
                                                   const int* __restrict__ inc,
                                                   float* n_out, float* n_in) {
  int g = blockIdx.x * 256 + threadIdx.x;
  n_out[g] = rsqrtf((float)outc[g] + 1.0f);
  n_in[g]  = rsqrtf((float)inc[g] + 1.0f);
}
__global__ __launch_bounds__(1024) void scan_kernel(const int* __restrict__ inc,
                                                    int* __restrict__ offs) {
  __shared__ int sums[1024];
  const int t = threadIdx.x;
  int x[8];
  const int base = t * 8;
  int s = 0;
  #pragma unroll
  for (int i = 0; i < 8; ++i) { int v = inc[base + i] + 1; x[i] = s; s += v; }
  sums[t] = s;
  __syncthreads();
  for (int off = 1; off < 1024; off <<= 1) {
    int a = (t >= off) ? sums[t - off] : 0;
    __syncthreads();
    sums[t] += a;
    __syncthreads();
  }
  const int pre = (t > 0) ? sums[t - 1] : 0;
  #pragma unroll
  for (int i = 0; i < 8; ++i) offs[base + i] = pre + x[i];
  if (t == 1023) offs[NN] = sums[1023];
}
__global__ __launch_bounds__(256) void copy_cur(const int* __restrict__ offs, int* cur) {
  int g = blockIdx.x * 256 + threadIdx.x;
  cur[g] = offs[g];
}
__global__ __launch_bounds__(256) void fill_csr(const int* __restrict__ src,
                                                const int* __restrict__ dst,
                                                int* cur, int* __restrict__ csr) {
  int g = blockIdx.x * 256 + threadIdx.x;   // EE + NN total
  int s, d;
  if (g < EE) { s = src[g]; d = dst[g]; }
  else        { s = g - EE; d = g - EE; }   // self-loops
  int pos = atomicAdd(&cur[d], 1);
  csr[pos] = s;
}
__global__ __launch_bounds__(256) void init_R(const float* __restrict__ type_emb,
                                              const int* __restrict__ nt,
                                              float* __restrict__ R) {
  int g = blockIdx.x * 256 + threadIdx.x;   // NN*4
  int n = g >> 2, c = g & 3;
  R[g] = type_emb[nt[n] * 4 + c];
}

// ---------------------------------------------------------------------------
// [M,256] @ [256,256] f32 register-tiled GEMM, 64x64 tile, 256 thr.
// ---------------------------------------------------------------------------
template<bool ROWSCALE, bool STORE, bool RED, typename CT>
__global__ __launch_bounds__(256) void gemm64_kernel(
    const float* __restrict__ A,
    const float* __restrict__ W,
    const float* __restrict__ rowscale,
    CT* __restrict__ C,
    const float* __restrict__ avec,
    float* __restrict__ SSo)
{
  const int m0 = blockIdx.x * 64;
  const int n0 = blockIdx.y * 64;
  const int t  = threadIdx.x;
  const int tr = t & 15, tc = t >> 4;
  __shared__ alignas(16) float As[32][68];
  __shared__ alignas(16) float Bs[32][68];
  __shared__ float red[64][2];
  float acc[4][4] = {};

  for (int ks = 0; ks < 8; ++ks) {
    const int k0 = ks * 32;
    #pragma unroll
    for (int rep = 0; rep < 8; ++rep) {
      int flat = rep * 256 + t;
      int r = flat >> 5, c = flat & 31;
      As[c][r] = A[(size_t)(m0 + r) * 256 + (k0 + c)];
      int rb = flat >> 6, cb = flat & 63;
      Bs[rb][cb] = W[(size_t)(k0 + rb) * 256 + (n0 + cb)];
    }
    __syncthreads();
    #pragma unroll
    for (int k = 0; k < 32; ++k) {
      const float4 a4 = *reinterpret_cast<const float4*>(&As[k][tr * 4]);
      const float4 b4 = *reinterpret_cast<const float4*>(&Bs[k][tc * 4]);
      const float av[4] = {a4.x, a4.y, a4.z, a4.w};
      const float bv[4] = {b4.x, b4.y, b4.z, b4.w};
      #pragma unroll
      for (int u = 0; u < 4; ++u)
        #pragma unroll
        for (int v = 0; v < 4; ++v)
          acc[u][v] = fmaf(av[u], bv[v], acc[u][v]);
    }
    __syncthreads();
  }

  if constexpr (ROWSCALE) {
    #pragma unroll
    for (int u = 0; u < 4; ++u) {
      float s = rowscale[m0 + tr * 4 + u];
      #pragma unroll
      for (int v = 0; v < 4; ++v) acc[u][v] *= s;
    }
  }
  if constexpr (STORE) {
    #pragma unroll
    for (int u = 0; u < 4; ++u) {
      size_t row = (size_t)(m0 + tr * 4 + u);
      #pragma unroll
      for (int v = 0; v < 4; ++v)
        storeC(&C[row * 256 + (n0 + tc * 4 + v)], acc[u][v]);
    }
  }
  if constexpr (RED) {
    if (t < 128) red[t >> 1][t & 1] = 0.f;
    __syncthreads();
    #pragma unroll
    for (int u = 0; u < 4; ++u) {
      float s = 0.f;
      #pragma unroll
      for (int v = 0; v < 4; ++v) {
        float x = acc[u][v];
        float lr = x > 0.f ? x : SLOPE * x;
        s += lr * avec[(tc * 4 + v) & 31];
      }
      atomicAdd(&red[tr * 4 + u][tc >> 3], s);
    }
    __syncthreads();
    if (t < 128) {
      int r = t >> 1, hh = t & 1;
      SSo[(size_t)(m0 + r) * 8 + blockIdx.y * 2 + hh] = red[r][hh];
    }
  }
}

// ---------------------------------------------------------------------------
// GCN aggregate / REConv / RKQ
// ---------------------------------------------------------------------------
__global__ __launch_bounds__(256) void agg_kernel(
    const int* __restrict__ offs, const int* __restrict__ csr,
    const float* __restrict__ X, const float* __restrict__ n_in,
    const float* __restrict__ bias, float* __restrict__ ghn)
{
  const int n = blockIdx.x, t = threadIdx.x;
  const int s0 = offs[n], s1 = offs[n + 1];
  float acc = 0.f;
  for (int i = s0; i < s1; ++i) acc += X[(size_t)csr[i] * 256 + t];
  ghn[(size_t)n * 256 + t] = fmaxf(fmaf(acc, n_in[n], bias[t]), 0.f);
}
__global__ __launch_bounds__(256) void re_proj(
    const float* __restrict__ R, const float* __restrict__ n_out,
    const float* __restrict__ Wre, const float* __restrict__ wtre,
    const int* __restrict__ nt, float* __restrict__ rtmp)
{
  int g = blockIdx.x * 256 + threadIdx.x;  // NN*4
  int n = g >> 2, j = g & 3;
  float s = 0.f;
  #pragma unroll
  for (int c = 0; c < 4; ++c) s += R[n * 4 + c] * Wre[c * 4 + j];
  rtmp[g] = s * n_out[n] * wtre[nt[n]];
}
__global__ __launch_bounds__(256) void re_agg(
    const int* __restrict__ offs, const int* __restrict__ csr,
    const float* __restrict__ rtmp, const float* __restrict__ n_in,
    const float* __restrict__ bre, float* __restrict__ Rn)
{
  int g = blockIdx.x * 256 + threadIdx.x;  // NN*4
  int n = g >> 2, j = g & 3;
  float a = 0.f;
  for (int i = offs[n]; i < offs[n + 1]; ++i) a += rtmp[csr[i] * 4 + j];
  Rn[g] = fmaxf(fmaf(a, n_in[n], bre[j]), 0.f);
}
__global__ __launch_bounds__(256) void rkq_kernel(
    const float* __restrict__ R, const float* __restrict__ Wrs,
    const float* __restrict__ Wrt, float* __restrict__ RKQ)
{
  int g = blockIdx.x * 256 + threadIdx.x;  // NN*128
  int n = g >> 7, c = g & 127;
  int which = c >> 5, cc = c & 31;
  const float* Wp = (which == 0) ? Wrs : (which == 1) ? Wrt
                   : (which == 2) ? (Wrs + 128) : (Wrt + 128);
  float s = 0.f;
  #pragma unroll
  for (int r = 0; r < 4; ++r) s += R[n * 4 + r] * Wp[r * 32 + cc];
  RKQ[g] = s;
}

// ---------------------------------------------------------------------------
// weight prep: Wg2 = diag(g1)Wr2, Wgl2 = diag(g1)Wl2
// ---------------------------------------------------------------------------
__global__ __launch_bounds__(256) void scale_w_kernel(
    const float* __restrict__ ln_g, const float* __restrict__ Wr2,
    const float* __restrict__ Wl2, float* __restrict__ Wg2,
    float* __restrict__ Wgl2)
{
  int g = blockIdx.x * 256 + threadIdx.x;  // 65536
  float s = ln_g[g >> 8];
  Wg2[g]  = s * Wr2[g];
  Wgl2[g] = s * Wl2[g];
}
// vecs[0]=g1@Wr2, [1]=b1@Wr2, [2]=g1@Wl2, [3]=b1@Wl2
__global__ __launch_bounds__(256) void vec4_kernel(
    const float* __restrict__ ln_g, const float* __restrict__ ln_b,
    const float* __restrict__ Wr2, const float* __restrict__ Wl2,
    float* __restrict__ vecs)
{
  const int which = blockIdx.x, t = threadIdx.x;
  const float* W = (which < 2) ? Wr2 : Wl2;
  const float* s = (which & 1) ? ln_b : ln_g;
  float a = 0.f;
  for (int k = 0; k < 256; ++k) a = fmaf(s[k], W[(size_t)k * 256 + t], a);
  vecs[which * 256 + t] = a;
}

// ---------------------------------------------------------------------------
// MEGA2: per batch (256 thr, ~73 KB LDS, 2 blocks/CU). Uses precomputed
// node tables so per-batch GEMMs & weight streams vanish:
//   GW  = GR1@Wfin1, GW2 = GR1@Wc2, GWL = GR1@Wcl (Wc2=Wfin1@diag(g1)Wr2,
//   Wcl = Wfin1@diag(g1)Wl2), GHG = gh@diag(g1)Wr2, GHL = gh@diag(g1)Wl2.
//   x  = p1◦GW[idx] + gh[idx]        (pre-LN layer1 state)
//   y  = p1◦GW2[idx] + GHG[idx]      (x@diag(g1)Wr2)
//   FR2_i = rs_i*y − rs_i*mu_i*v1 + v2 ; sl2 via z0 = p1r0◦GWL + GHL
// Writes: ret1, h1row0 buf, ctx2 buf (epilogue GEMM finishes ret2).
// ---------------------------------------------------------------------------
__global__ __launch_bounds__(256, 2) void mega2_kernel(
    const int* __restrict__ seqs,
    const float* __restrict__ gh,
    const ushortT* __restrict__ GW, const ushortT* __restrict__ GW2,
    const ushortT* __restrict__ GWL, const ushortT* __restrict__ GHG,
    const ushortT* __restrict__ GHL,
    const float* __restrict__ SLg, const float* __restrict__ SRg,
    const float* __restrict__ RKQ,
    const float* __restrict__ vecs,           // v1,v2,vl1,vl2
    const float* __restrict__ al2, const float* __restrict__ ar2,
    const float* __restrict__ ln_g, const float* __restrict__ ln_b,
    float* __restrict__ h1r0buf, float* __restrict__ ctx2buf,
    float* __restrict__ out)
{
  __shared__ int     idx[32];
  __shared__ ushortT GWs[32][264];
  __shared__ ushortT GW2s[32][264];
  __shared__ ushortT FR2s[32][268];
  __shared__ float SLs[8][32], SRs[8][32];
  __shared__ float RKs[32][36], RQs[32][36], RQ2s[32][36];
  __shared__ float p1r0[8][32];
  __shared__ float part[32][8];
  __shared__ float mu_s[32], rs_s[32];
  __shared__ float SR2s[8][32];
  __shared__ float sl2s[8];
  __shared__ float rk2s[32];
  __shared__ float scp[8][32];
  __shared__ float h1r0s[256];
  __shared__ float nrm1s;

  const int b = blockIdx.x, t = threadIdx.x;
  const int h8 = t >> 5, lo = t & 31;
  const int c0 = h8 * 32;
  const float* v1  = vecs;
  const float* v2  = vecs + 256;
  const float* vl1 = vecs + 512;
  const float* vl2 = vecs + 768;

  if (t < 32) idx[t] = seqs[b * 32 + t];
  __syncthreads();

  for (int s = 0; s < 32; ++s) {
    GWs[s][t]  = GW [(size_t)idx[s] * 256 + t];
    GW2s[s][t] = GW2[(size_t)idx[s] * 256 + t];
  }
  SLs[h8][lo] = SLg[(size_t)idx[lo] * 8 + h8];
  SRs[h8][lo] = SRg[(size_t)idx[lo] * 8 + h8];
  #pragma unroll
  for (int rep = 0; rep < 4; ++rep) {
    int flat = rep * 256 + t, s3 = flat >> 5, c3 = flat & 31;
    RKs[s3][c3]  = RKQ[(size_t)idx[s3] * 128 + c3];
    RQs[s3][c3]  = RKQ[(size_t)idx[s3] * 128 + 32 + c3];
    RQ2s[s3][c3] = RKQ[(size_t)idx[s3] * 128 + 96 + c3];
  }
  if (t < 32) rk2s[t] = RKQ[(size_t)idx[0] * 128 + 64 + t];
  __syncthreads();

  // ---- attn1 scores+softmax: thread = (head h8, query row lo) ----
  float p1[32];
  {
    const float rk0 = RKs[lo][h8 * 4 + 0], rk1 = RKs[lo][h8 * 4 + 1],
                rk2 = RKs[lo][h8 * 4 + 2], rk3 = RKs[lo][h8 * 4 + 3];
    const float sli = SLs[h8][lo];
    float m = -1e30f;
    #pragma unroll
    for (int j = 0; j < 32; ++j) {
      float sc = sli + SRs[h8][j]
               + rk0 * RQs[j][h8 * 4 + 0] + rk1 * RQs[j][h8 * 4 + 1]
               + rk2 * RQs[j][h8 * 4 + 2] + rk3 * RQs[j][h8 * 4 + 3];
      p1[j] = sc; m = fmaxf(m, sc);
    }
    float sum = 0.f;
    #pragma unroll
    for (int j = 0; j < 32; ++j) { p1[j] = __expf(p1[j] - m); sum += p1[j]; }
    const float inv = 1.f / sum;
    #pragma unroll
    for (int j = 0; j < 32; ++j) p1[j] *= inv;
  }
  if (lo == 0) {
    #pragma unroll
    for (int j = 0; j < 32; ++j) p1r0[h8][j] = p1[j];
  }

  // ---- combines: x = p1◦GW + gh[idx_lo] ; y = p1◦GW2 + GHG[idx_lo] ----
  float x[32], y[32];
  #pragma unroll
  for (int d = 0; d < 32; ++d) { x[d] = 0.f; y[d] = 0.f; }
  #pragma unroll
  for (int j = 0; j < 32; ++j) {
    const float pj = p1[j];
    const uintT* rx = reinterpret_cast<const uintT*>(&GWs[j][c0]);
    const uintT* ry = reinterpret_cast<const uintT*>(&GW2s[j][c0]);
    #pragma unroll
    for (int q = 0; q < 16; ++q) {
      const uintT ax = rx[q], ay = ry[q];
      x[2 * q + 0] = fmaf(pj, blo(ax), x[2 * q + 0]);
      x[2 * q + 1] = fmaf(pj, bhi(ax), x[2 * q + 1]);
      y[2 * q + 0] = fmaf(pj, blo(ay), y[2 * q + 0]);
      y[2 * q + 1] = fmaf(pj, bhi(ay), y[2 * q + 1]);
    }
  }
  {
    const int my = idx[lo];
    const float*   gp = &gh [(size_t)my * 256 + c0];
    const ushortT* hp = &GHG[(size_t)my * 256 + c0];
    #pragma unroll
    for (int d = 0; d < 32; ++d) { x[d] += gp[d]; y[d] += b2f(hp[d]); }
  }

  // ---- LN stats over x (row lo distributed over 8 heads) ----
  {
    float s = 0.f;
    #pragma unroll
    for (int d = 0; d < 32; ++d) s += x[d];
    part[lo][h8] = s;
  }
  __syncthreads();
  if (t < 32) {
    float m = 0.f;
    #pragma unroll
    for (int h = 0; h < 8; ++h) m += part[t][h];
    mu_s[t] = m * (1.f / 256.f);
  }
  __syncthreads();
  const float mu = mu_s[lo];
  {
    float v = 0.f;
    #pragma unroll
    for (int d = 0; d < 32; ++d) { float dd = x[d] - mu; v += dd * dd; }
    part[lo][h8] = v;
  }
  __syncthreads();
  if (t < 32) {
    float m = 0.f;
    #pragma unroll
    for (int h = 0; h < 8; ++h) m += part[t][h];
    rs_s[t] = rsqrtf(m * (1.f / 256.f) + LN_EPS);
  }
  __syncthreads();
  const float rs = rs_s[lo];
  const float rm = rs * mu;

  // ---- FR2 (bf16 to LDS) + SR2 per (head,row) ----
  {
    float sr2 = 0.f;
    uintT* fw = reinterpret_cast<uintT*>(&FR2s[lo][0]) + (c0 >> 1);
    #pragma unroll
    for (int q = 0; q < 16; ++q) {
      const int c = c0 + 2 * q;
      float fa = fmaf(rs, y[2 * q + 0], fmaf(-rm, v1[c],     v2[c]));
      float fb = fmaf(rs, y[2 * q + 1], fmaf(-rm, v1[c + 1], v2[c + 1]));
      fw[q] = (uintT)f2bu(fa) | ((uintT)f2bu(fb) << 16);
      float la = fa > 0.f ? fa : SLOPE * fa;
      float lb = fb > 0.f ? fb : SLOPE * fb;
      sr2 = fmaf(la, ar2[2 * q], fmaf(lb, ar2[2 * q + 1], sr2));
    }
    SR2s[h8][lo] = sr2;
  }

  // ---- h1 row 0 (LN applied) + ret1 partials ----
  if (lo == 0) {
    float sq = 0.f;
    #pragma unroll
    for (int d = 0; d < 32; ++d) {
      const int c = c0 + d;
      float hv = fmaf((x[d] - mu) * rs, ln_g[c], ln_b[c]);
      h1r0s[c] = hv;
      h1r0buf[(size_t)b * 256 + c] = hv;
      sq += hv * hv;
    }
    part[0][h8] = sq;   // safe: prior part reads completed before last sync
  }
  __syncthreads();

  // ---- fl2 row0 via tables: z0 = p1r0◦GWL + GHL[idx0] ; sl2 per head ----
  {
    float z0 = 0.f;
    #pragma unroll 8
    for (int j = 0; j < 32; ++j)
      z0 = fmaf(p1r0[h8][j], b2f(GWL[(size_t)idx[j] * 256 + t]), z0);
    z0 += b2f(GHL[(size_t)idx[0] * 256 + t]);
    const float rs0 = rs_s[0], rm0 = rs_s[0] * mu_s[0];
    float fl = fmaf(rs0, z0, fmaf(-rm0, vl1[t], vl2[t]));
    float lr = (fl > 0.f ? fl : SLOPE * fl) * al2[lo];
    lr = red32(lr);
    if (lo == 0) sl2s[h8] = lr;
  }
  if (t == 0) {
    float s = 0.f;
    #pragma unroll
    for (int h = 0; h < 8; ++h) s += part[0][h];
    nrm1s = 1.f / fmaxf(sqrtf(s), 1e-12f);
  }
  __syncthreads();
  out[(size_t)b * 768 + 256 + t] = h1r0s[t] * nrm1s;

  // ---- attn2 row0: thread = (head h8, key lo) ----
  {
    float s2 = sl2s[h8] + SR2s[h8][lo]
             + rk2s[h8 * 4 + 0] * RQ2s[lo][h8 * 4 + 0]
             + rk2s[h8 * 4 + 1] * RQ2s[lo][h8 * 4 + 1]
             + rk2s[h8 * 4 + 2] * RQ2s[lo][h8 * 4 + 2]
             + rk2s[h8 * 4 + 3] * RQ2s[lo][h8 * 4 + 3];
    float m2 = max32(s2);
    float e = __expf(s2 - m2);
    float su = red32(e);
    scp[h8][lo] = e / su;
  }
  __syncthreads();

  // ---- ctx2 = p2 ◦ FR2 (thread = col t) ----
  {
    float a = 0.f;
    #pragma unroll
    for (int j = 0; j < 32; ++j) a = fmaf(scp[h8][j], b2f(FR2s[j][t]), a);
    ctx2buf[(size_t)b * 256 + t] = a;
  }
}

// ---------------------------------------------------------------------------
// Epilogue: ret2 = l2n(LN(h1row0 + ctx2 @ Wfin2))  — 64 rows/block
// ---------------------------------------------------------------------------
__global__ __launch_bounds__(256) void final_ln_kernel(
    const float* __restrict__ A,       // ctx2buf [8192,256]
    const float* __restrict__ W,       // Wfin2
    const float* __restrict__ res,     // h1r0buf [8192,256]
    const float* __restrict__ lng, const float* __restrict__ lnb,
    float* __restrict__ out)
{
  const int m0 = blockIdx.x * 64;
  const int t  = threadIdx.x;
  const int tr = t & 15, tc = t >> 4;
  __shared__ alignas(16) float As[32][68];
  __shared__ alignas(16) float Bs[32][264];
  __shared__ float red[64][16];
  __shared__ float stat[64];
  float acc[4][16] = {};

  for (int ks = 0; ks < 8; ++ks) {
    const int k0 = ks * 32;
    #pragma unroll
    for (int rep = 0; rep < 8; ++rep) {
      int flat = rep * 256 + t;
      int r = flat >> 5, c = flat & 31;
      As[c][r] = A[(size_t)(m0 + r) * 256 + (k0 + c)];
    }
    #pragma unroll
    for (int rep = 0; rep < 32; ++rep) {
      int flat = rep * 256 + t;
      int rb = flat >> 8, cb = flat & 255;
      Bs[rb][cb] = W[(size_t)(k0 + rb) * 256 + cb];
    }
    __syncthreads();
    #pragma unroll
    for (int k = 0; k < 32; ++k) {
      const float4 a4 = *reinterpret_cast<const float4*>(&As[k][tr * 4]);
      const float av[4] = {a4.x, a4.y, a4.z, a4.w};
      #pragma unroll
      for (int q = 0; q < 4; ++q) {
        const float4 b4 = *reinterpret_cast<const float4*>(&Bs[k][tc * 16 + q * 4]);
        const float bv[4] = {b4.x, b4.y, b4.z, b4.w};
        #pragma unroll
        for (int u = 0; u < 4; ++u)
          #pragma unroll
          for (int v = 0; v < 4; ++v)
            acc[u][q * 4 + v] = fmaf(av[u], bv[v], acc[u][q * 4 + v]);
      }
    }
    __syncthreads();
  }

  int rows[4];
  #pragma unroll
  for (int u = 0; u < 4; ++u) rows[u] = m0 + tr * 4 + u;

  #pragma unroll
  for (int u = 0; u < 4; ++u) {
    const float* rp = &res[(size_t)rows[u] * 256 + tc * 16];
    #pragma unroll
    for (int v = 0; v < 16; ++v) acc[u][v] += rp[v];
  }
  #pragma unroll
  for (int u = 0; u < 4; ++u) {
    float s = 0.f;
    #pragma unroll
    for (int v = 0; v < 16; ++v) s += acc[u][v];
    red[tr * 4 + u][tc] = s;
  }
  __syncthreads();
  if (t < 64) {
    float s = 0.f;
    #pragma unroll
    for (int g = 0; g < 16; ++g) s += red[t][g];
    stat[t] = s * (1.0f / 256.0f);
  }
  __syncthreads();
  float mu[4];
  #pragma unroll
  for (int u = 0; u < 4; ++u) mu[u] = stat[tr * 4 + u];
  #pragma unroll
  for (int u = 0; u < 4; ++u) {
    float s = 0.f;
    #pragma unroll
    for (int v = 0; v < 16; ++v) { float d = acc[u][v] - mu[u]; s += d * d; }
    red[tr * 4 + u][tc] = s;
  }
  __syncthreads();
  if (t < 64) {
    float s = 0.f;
    #pragma unroll
    for (int g = 0; g < 16; ++g) s += red[t][g];
    stat[t] = rsqrtf(s * (1.0f / 256.0f) + LN_EPS);
  }
  __syncthreads();
  float rst[4];
  #pragma unroll
  for (int u = 0; u < 4; ++u) rst[u] = stat[tr * 4 + u];
  #pragma unroll
  for (int u = 0; u < 4; ++u) {
    float s = 0.f;
    #pragma unroll
    for (int v = 0; v < 16; ++v) {
      int col = tc * 16 + v;
      float yv = fmaf((acc[u][v] - mu[u]) * rst[u], lng[col], lnb[col]);
      acc[u][v] = yv;
      s += yv * yv;
    }
    red[tr * 4 + u][tc] = s;
  }
  __syncthreads();
  if (t < 64) {
    float s = 0.f;
    #pragma unroll
    for (int g = 0; g < 16; ++g) s += red[t][g];
    stat[t] = 1.0f / fmaxf(sqrtf(s), 1e-12f);
  }
  __syncthreads();
  #pragma unroll
  for (int u = 0; u < 4; ++u) {
    float rn = stat[tr * 4 + u];
    #pragma unroll
    for (int v = 0; v < 16; ++v)
      out[(size_t)rows[u] * 768 + 512 + tc * 16 + v] = acc[u][v] * rn;
  }
}

// ---------------------------------------------------------------------------
extern "C" void kernel_launch(void* const* d_in, const int* in_sizes, int n_in,
                              void* d_out, int out_size, void* d_ws, size_t ws_size,
                              hipStream_t stream)
{
  (void)in_sizes; (void)n_in; (void)out_size; (void)ws_size;

  const float* feat[4]; const float* wfc[4]; const float* bfc[4];
  for (int i = 0; i < 4; ++i) {
    feat[i] = (const float*)d_in[i * 3 + 0];
    wfc[i]  = (const float*)d_in[i * 3 + 1];
    bfc[i]  = (const float*)d_in[i * 3 + 2];
  }
  const float* type_emb = (const float*)d_in[12];
  const float* Wgcn = (const float*)d_in[13];
  const float* bgcn = (const float*)d_in[14];
  const float* Wre  = (const float*)d_in[15];
  const float* bre  = (const float*)d_in[16];
  const float* wtre = (const float*)d_in[17];
  const float* Wl   = (const float*)d_in[18];
  const float* Wr   = (const float*)d_in[19];
  const float* al   = (const float*)d_in[20];
  const float* ar   = (const float*)d_in[21];
  const float* Wrs  = (const float*)d_in[22];
  const float* Wrt  = (const float*)d_in[23];
  const float* Wfin = (const float*)d_in[24];
  const float* ln_g = (const float*)d_in[25];
  const float* ln_b = (const float*)d_in[26];
  const int* src       = (const int*)d_in[27];
  const int* dst       = (const int*)d_in[28];
  const int* node_type = (const int*)d_in[29];
  const int* seqs      = (const int*)d_in[30];
  float* out = (float*)d_out;

  // workspace carve-up (~50 MB)
  char* p = (char*)d_ws;
  auto take = [&](size_t n) { char* q = p; p += (n + 255) & ~(size_t)255; return q; };
  float* gh    = (float*)take((size_t)NN * 256 * 4);
  float* Xbuf  = (float*)take((size_t)NN * 256 * 4);   // GCN scratch, then ctx2buf
  float* GR1   = (float*)take((size_t)NN * 256 * 4);   // gh@Wr1, then h1r0buf
  float* RKQ   = (float*)take((size_t)NN * 128 * 4);
  float* SLg   = (float*)take((size_t)NN * 8 * 4);
  float* SRg   = (float*)take((size_t)NN * 8 * 4);
  float* n_out = (float*)take((size_t)NN * 4);
  float* n_in_ = (float*)take((size_t)NN * 4);
  int*   outc  = (int*)take((size_t)NN * 4);
  int*   inc   = (int*)take((size_t)NN * 4);
  int*   offs  = (int*)take((size_t)(NN + 1) * 4);
  int*   cur   = (int*)take((size_t)NN * 4);
  int*   csr   = (int*)take((size_t)(EE + NN) * 4);
  float* R     = (float*)take((size_t)NN * 4 * 4);
  float* rtmp  = (float*)take((size_t)NN * 4 * 4);
  ushortT* GW  = (ushortT*)take((size_t)NN * 256 * 2);
  ushortT* GW2 = (ushortT*)take((size_t)NN * 256 * 2);
  ushortT* GWL = (ushortT*)take((size_t)NN * 256 * 2);
  ushortT* GHG = (ushortT*)take((size_t)NN * 256 * 2);
  ushortT* GHL = (ushortT*)take((size_t)NN * 256 * 2);
  float* Wg2   = (float*)take((size_t)65536 * 4);
  float* Wgl2  = (float*)take((size_t)65536 * 4);
  float* Wc2   = (float*)take((size_t)65536 * 4);
  float* Wcl   = (float*)take((size_t)65536 * 4);
  float* vecs  = (float*)take((size_t)4 * 256 * 4);
  float* ctx2buf = Xbuf;   // alias: Xbuf dead after GCN
  float* h1r0buf = GR1;    // alias: GR1 dead after table GEMMs

  const float* Wr2 = Wr + 65536;
  const float* Wl2 = Wl + 65536;

  // 1) FC + ret0
  fc_kernel<<<256, 256, 0, stream>>>(feat[0], feat[1], feat[2], feat[3],
                                     wfc[0], wfc[1], wfc[2], wfc[3],
                                     bfc[0], bfc[1], bfc[2], bfc[3], gh, out);
  // 2) degrees + CSR
  zero_counts<<<64, 256, 0, stream>>>(outc, inc);
  count_deg<<<512, 256, 0, stream>>>(src, dst, outc, inc);
  norm_kernel<<<32, 256, 0, stream>>>(outc, inc, n_out, n_in_);
  scan_kernel<<<1, 1024, 0, stream>>>(inc, offs);
  copy_cur<<<32, 256, 0, stream>>>(offs, cur);
  fill_csr<<<544, 256, 0, stream>>>(src, dst, cur, csr);
  init_R<<<128, 256, 0, stream>>>(type_emb, node_type, R);

  // weight prep (independent of graph work)
  scale_w_kernel<<<256, 256, 0, stream>>>(ln_g, Wr2, Wl2, Wg2, Wgl2);
  vec4_kernel<<<4, 256, 0, stream>>>(ln_g, ln_b, Wr2, Wl2, vecs);
  gemm64_kernel<false, true, false, float>
      <<<dim3(4, 4), 256, 0, stream>>>(Wfin, Wg2, nullptr, Wc2, nullptr, nullptr);
  gemm64_kernel<false, true, false, float>
      <<<dim3(4, 4), 256, 0, stream>>>(Wfin, Wgl2, nullptr, Wcl, nullptr, nullptr);

  // 3) GCN + REConv, K=2
  for (int k = 0; k < 2; ++k) {
    gemm64_kernel<true, true, false, float>
        <<<dim3(128, 4), 256, 0, stream>>>(gh, Wgcn + (size_t)k * 65536,
                                           n_out, Xbuf, nullptr, nullptr);
    agg_kernel<<<NN, 256, 0, stream>>>(offs, csr, Xbuf, n_in_, bgcn + k * 256, gh);
    re_proj<<<128, 256, 0, stream>>>(R, n_out, Wre + k * 16, wtre + k * 4, node_type, rtmp);
    re_agg<<<128, 256, 0, stream>>>(offs, csr, rtmp, n_in_, bre + k * 4, R);
  }

  // 4) attention precomputes + node tables
  rkq_kernel<<<4096, 256, 0, stream>>>(R, Wrs, Wrt, RKQ);
  gemm64_kernel<false, false, true, float>
      <<<dim3(128, 4), 256, 0, stream>>>(gh, Wl, nullptr, (float*)nullptr, al, SLg);
  gemm64_kernel<false, true, true, float>
      <<<dim3(128, 4), 256, 0, stream>>>(gh, Wr, nullptr, GR1, ar, SRg);
  gemm64_kernel<false, true, false, ushortT>
      <<<dim3(128, 4), 256, 0, stream>>>(GR1, Wfin, nullptr, GW, nullptr, nullptr);
  gemm64_kernel<false, true, false, ushortT>
      <<<dim3(128, 4), 256, 0, stream>>>(GR1, Wc2, nullptr, GW2, nullptr, nullptr);
  gemm64_kernel<false, true, false, ushortT>
      <<<dim3(128, 4), 256, 0, stream>>>(GR1, Wcl, nullptr, GWL, nullptr, nullptr);
  gemm64_kernel<false, true, false, ushortT>
      <<<dim3(128, 4), 256, 0, stream>>>(gh, Wg2, nullptr, GHG, nullptr, nullptr);
  gemm64_kernel<false, true, false, ushortT>
      <<<dim3(128, 4), 256, 0, stream>>>(gh, Wgl2, nullptr, GHL, nullptr, nullptr);

  // 5) fused transformer (tables) -> ret1, h1row0, ctx2
  mega2_kernel<<<NN, 256, 0, stream>>>(seqs, gh, GW, GW2, GWL, GHG, GHL,
                                       SLg, SRg, RKQ, vecs,
                                       al + 32, ar + 32, ln_g, ln_b,
                                       h1r0buf, ctx2buf, out);

  // 6) epilogue: ret2 = l2n(LN(h1row0 + ctx2@Wfin2))
  final_ln_kernel<<<128, 256, 0, stream>>>(ctx2buf, Wfin + 65536, h1r0buf,
                                           ln_g + 256, ln_b + 256, out);
}